// Round 1
// baseline (271.044 us; speedup 1.0000x reference)
//
#include <hip/hip_runtime.h>
#include <math.h>

// Problem constants (LayerNorm_v2: B=8, S=4096, D=1024, f32 in / f32 out)
#define BB 8
#define SS 4096
#define DD 1024
#define EPSF 1e-5f

// ---------------------------------------------------------------------------
// Kernel 1: per-row "buggy Welford" scan, replicating the reference exactly:
//   for k = 1..D:  mean = (mean + d_k)/k ;  var += (d_k - mean)^2
//   var /= (D-1);  rstd = rsqrt(var + eps)
// Stats come from batch 0 only (x[0]) and are broadcast over batches later.
// ---------------------------------------------------------------------------
constexpr int ROWS    = 8;          // rows (sequence positions) per block
constexpr int TPB1    = 64;         // one wave per block
constexpr int R4      = DD / 4;     // 256 float4 per row
constexpr int LSTRIDE = R4 + 1;     // 257: odd float4 stride -> conflict-free scan reads

__global__ __launch_bounds__(TPB1) void stats_kernel(
    const float* __restrict__ x,
    float* __restrict__ mean_out,
    float* __restrict__ rstd_out)
{
    __shared__ float4 tile[ROWS * LSTRIDE];   // 8 * 257 * 16B = ~32.9 KB

    const int tid  = threadIdx.x;
    const int row0 = blockIdx.x * ROWS;
    const float4* __restrict__ x4 =
        reinterpret_cast<const float4*>(x) + (size_t)row0 * R4;

    // Cooperative coalesced staging: 8 rows x 256 float4.
    for (int idx = tid; idx < ROWS * R4; idx += TPB1) {
        const int r  = idx >> 8;          // idx / 256
        const int j4 = idx & (R4 - 1);    // idx % 256
        tile[r * LSTRIDE + j4] = x4[(size_t)r * R4 + j4];
    }
    __syncthreads();

    if (tid < ROWS) {
        float mean = 0.0f, var = 0.0f;
        const float4* rowp = &tile[tid * LSTRIDE];
        for (int jf = 0; jf < R4; ++jf) {
            const float4 v = rowp[jf];
            const float base = (float)(jf * 4);   // exact for <= 1020
            // k = 4*jf + {1,2,3,4};  1/k via v_rcp_f32 (<=1 ulp, damped by recurrence)
            const float r0 = __builtin_amdgcn_rcpf(base + 1.0f);
            const float r1 = __builtin_amdgcn_rcpf(base + 2.0f);
            const float r2 = __builtin_amdgcn_rcpf(base + 3.0f);
            const float r3 = __builtin_amdgcn_rcpf(base + 4.0f);
            // mean = (mean + d)/k  ==  fma(mean, 1/k, d*(1/k));  d*(1/k) off critical path
            mean = fmaf(mean, r0, v.x * r0); { const float t = v.x - mean; var = fmaf(t, t, var); }
            mean = fmaf(mean, r1, v.y * r1); { const float t = v.y - mean; var = fmaf(t, t, var); }
            mean = fmaf(mean, r2, v.z * r2); { const float t = v.z - mean; var = fmaf(t, t, var); }
            mean = fmaf(mean, r3, v.w * r3); { const float t = v.w - mean; var = fmaf(t, t, var); }
        }
        var *= (1.0f / 1023.0f);              // var / (D-1)
        mean_out[row0 + tid] = mean;
        rstd_out[row0 + tid] = rsqrtf(var + EPSF);
    }
}

// ---------------------------------------------------------------------------
// Kernel 2: streaming normalize.  out[b,s,d] = alpha[d]*(x[b,s,d]-mean[s])*rstd[s] + beta[d]
// One float4 per thread; fully coalesced read+write.
// ---------------------------------------------------------------------------
constexpr int TPB2 = 256;

__global__ __launch_bounds__(TPB2) void norm_kernel(
    const float* __restrict__ x,
    const float* __restrict__ alpha,
    const float* __restrict__ beta,
    const float* __restrict__ meanp,
    const float* __restrict__ rstdp,
    float* __restrict__ out)
{
    const size_t i4 = (size_t)blockIdx.x * TPB2 + threadIdx.x;  // float4 index
    const int d4 = (int)(i4 & (size_t)(R4 - 1));                // (4*i4 % 1024)/4
    const int s  = (int)((i4 >> 8) & (size_t)(SS - 1));         // row within batch

    const float4 xv = reinterpret_cast<const float4*>(x)[i4];
    const float4 av = reinterpret_cast<const float4*>(alpha)[d4];
    const float4 bv = reinterpret_cast<const float4*>(beta)[d4];
    const float  m  = meanp[s];
    const float  r  = rstdp[s];

    float4 o;
    o.x = fmaf(av.x * (xv.x - m), r, bv.x);
    o.y = fmaf(av.y * (xv.y - m), r, bv.y);
    o.z = fmaf(av.z * (xv.z - m), r, bv.z);
    o.w = fmaf(av.w * (xv.w - m), r, bv.w);
    reinterpret_cast<float4*>(out)[i4] = o;
}

extern "C" void kernel_launch(void* const* d_in, const int* in_sizes, int n_in,
                              void* d_out, int out_size, void* d_ws, size_t ws_size,
                              hipStream_t stream) {
    (void)in_sizes; (void)n_in; (void)out_size; (void)ws_size;
    const float* x     = (const float*)d_in[0];   // (8, 4096, 1024) f32
    const float* alpha = (const float*)d_in[1];   // (1024,) f32
    const float* beta  = (const float*)d_in[2];   // (1024,) f32
    float* out     = (float*)d_out;
    float* mean_ws = (float*)d_ws;                // 4096 floats
    float* rstd_ws = mean_ws + SS;                // 4096 floats

    // Kernel 1: stats over x[0] (4096 rows).
    hipLaunchKernelGGL(stats_kernel, dim3(SS / ROWS), dim3(TPB1), 0, stream,
                       x, mean_ws, rstd_ws);

    // Kernel 2: normalize all B*S*D elements, float4 per thread.
    const int n4 = (BB * SS * DD) / 4;            // 8388608
    hipLaunchKernelGGL(norm_kernel, dim3(n4 / TPB2), dim3(TPB2), 0, stream,
                       x, alpha, beta, mean_ws, rstd_ws, out);
}

// Round 3
// 229.533 us; speedup vs baseline: 1.1808x; 1.1808x over previous
//
#include <hip/hip_runtime.h>
#include <math.h>

// LayerNorm_v2: B=8, S=4096, D=1024, f32 in / f32 out.
// Reference quirks replicated:
//  - stats from batch 0 only, broadcast over all batches
//  - "buggy Welford": mean_k=(mean_{k-1}+d_k)/k ; var += (d_k-mean_k)^2 ; var/=(D-1)
#define BB 8
#define SS 4096
#define DD 1024
#define EPSF 1e-5f

// Native vector type for nontemporal builtins (HIP_vector_type is a struct
// and is rejected by __builtin_nontemporal_*).
typedef float f32x4 __attribute__((ext_vector_type(4)));

// ---------------------------------------------------------------------------
// Kernel 1: fully parallel stats, one wave per row.
// The recurrence forgets history factorially:
//   mean_j = arr[j-1]/j + arr[j-2]/(j(j-1)) + arr[j-3]/(j(j-1)(j-2)) + ...
// Lane L seeds mean_{16L} with a 6-term Horner series (trunc err ~1e-6 at
// j=16), then runs its 16 recurrence steps exactly. Wave-reduce var.
// ---------------------------------------------------------------------------
__global__ __launch_bounds__(64) void stats_kernel(
    const float* __restrict__ x,
    float* __restrict__ mean_out,
    float* __restrict__ rstd_out)
{
    const int row = blockIdx.x;           // 0..4095 (batch 0 rows)
    const int L   = threadIdx.x;          // 0..63; lane L owns k in [16L+1, 16L+16]
    const float4* __restrict__ rowp =
        reinterpret_cast<const float4*>(x) + (size_t)row * (DD / 4);

    // Own 16 floats: float4 indices 4L..4L+3.
    const float4 a0 = rowp[4 * L + 0];
    const float4 a1 = rowp[4 * L + 1];
    const float4 a2 = rowp[4 * L + 2];
    const float4 a3 = rowp[4 * L + 3];
    const float d[16] = { a0.x, a0.y, a0.z, a0.w,  a1.x, a1.y, a1.z, a1.w,
                          a2.x, a2.y, a2.z, a2.w,  a3.x, a3.y, a3.z, a3.w };

    // Seed mean_{16L} from the 6 preceding elements (closed-form series).
    float m = 0.0f;
    if (L > 0) {
        const float4 p0 = rowp[4 * L - 2];   // floats 16L-8 .. 16L-5
        const float4 p1 = rowp[4 * L - 1];   // floats 16L-4 .. 16L-1
        const float jf = (float)(16 * L);
        float acc = p0.z;                                          // arr[j-6]
        acc = fmaf(acc, __builtin_amdgcn_rcpf(jf - 5.0f), p0.w);   // arr[j-5] + acc/(j-5)
        acc = fmaf(acc, __builtin_amdgcn_rcpf(jf - 4.0f), p1.x);
        acc = fmaf(acc, __builtin_amdgcn_rcpf(jf - 3.0f), p1.y);
        acc = fmaf(acc, __builtin_amdgcn_rcpf(jf - 2.0f), p1.z);
        acc = fmaf(acc, __builtin_amdgcn_rcpf(jf - 1.0f), p1.w);
        m = acc * __builtin_amdgcn_rcpf(jf);
    }

    // 16 exact recurrence steps.
    float var = 0.0f;
    const float base = (float)(16 * L);
#pragma unroll
    for (int t = 0; t < 16; ++t) {
        const float rk = __builtin_amdgcn_rcpf(base + (float)(t + 1));  // 1/k
        m = (m + d[t]) * rk;
        const float df = d[t] - m;
        var = fmaf(df, df, var);
    }

    // Wave reduction of var; lane 63 holds mean_1024.
#pragma unroll
    for (int off = 32; off >= 1; off >>= 1) var += __shfl_down(var, off, 64);
    const float mean_final = __shfl(m, 63, 64);

    if (L == 0) {
        mean_out[row] = mean_final;
        rstd_out[row] = rsqrtf(var * (1.0f / 1023.0f) + EPSF);
    }
}

// ---------------------------------------------------------------------------
// Kernel 2: streaming normalize. One block = one row (256 float4), so
// mean/rstd indices are block-uniform (scalar loads). Nontemporal on the
// 268 MB x/out stream to avoid L2 write-allocate pollution.
// ---------------------------------------------------------------------------
__global__ __launch_bounds__(256) void norm_kernel(
    const float* __restrict__ x,
    const float* __restrict__ alpha,
    const float* __restrict__ beta,
    const float* __restrict__ meanp,
    const float* __restrict__ rstdp,
    float* __restrict__ out)
{
    const int tid  = threadIdx.x;                 // 0..255 = float4 index in row
    const int brow = blockIdx.x;                  // 0..B*S-1
    const int s    = brow & (SS - 1);             // row within batch (uniform)

    const float m = meanp[s];
    const float r = rstdp[s];

    const size_t i4 = (size_t)brow * 256 + tid;
    const f32x4 xv = __builtin_nontemporal_load(
        reinterpret_cast<const f32x4*>(x) + i4);
    const float4 av = reinterpret_cast<const float4*>(alpha)[tid];
    const float4 bv = reinterpret_cast<const float4*>(beta)[tid];

    f32x4 o;
    o.x = fmaf(av.x * (xv.x - m), r, bv.x);
    o.y = fmaf(av.y * (xv.y - m), r, bv.y);
    o.z = fmaf(av.z * (xv.z - m), r, bv.z);
    o.w = fmaf(av.w * (xv.w - m), r, bv.w);
    __builtin_nontemporal_store(o, reinterpret_cast<f32x4*>(out) + i4);
}

extern "C" void kernel_launch(void* const* d_in, const int* in_sizes, int n_in,
                              void* d_out, int out_size, void* d_ws, size_t ws_size,
                              hipStream_t stream) {
    (void)in_sizes; (void)n_in; (void)out_size; (void)ws_size;
    const float* x     = (const float*)d_in[0];   // (8, 4096, 1024) f32
    const float* alpha = (const float*)d_in[1];   // (1024,) f32
    const float* beta  = (const float*)d_in[2];   // (1024,) f32
    float* out     = (float*)d_out;
    float* mean_ws = (float*)d_ws;                // 4096 floats
    float* rstd_ws = mean_ws + SS;                // 4096 floats

    hipLaunchKernelGGL(stats_kernel, dim3(SS), dim3(64), 0, stream,
                       x, mean_ws, rstd_ws);
    hipLaunchKernelGGL(norm_kernel, dim3(BB * SS), dim3(256), 0, stream,
                       x, alpha, beta, mean_ws, rstd_ws, out);
}